// Round 7
// baseline (520.097 us; speedup 1.0000x reference)
//
#include <hip/hip_runtime.h>
#include <hip/hip_bf16.h>

#define N_NODES 50000
#define N_HALF  25000
#define N_EDGES 800000
#define F_IN    256
#define H_DIM   64
#define C_DIM   16
#define PE_CNT  200000

typedef __hip_bfloat16 bf16;

__device__ __forceinline__ float b2f(bf16 v) { return __bfloat162float(v); }
__device__ __forceinline__ bf16  f2b(float v) { return __float2bfloat16(v); }
__device__ __forceinline__ unsigned short f2b_u(float v) {
    union { bf16 b; unsigned short u; } cv; cv.b = __float2bfloat16(v); return cv.u;
}

// ---------------- CSR build (rows partitioned lo-src | hi-src) ----------------

// counts per dst: total + lo(src<N_HALF); block 0 packs Wh[64][32] = [Wa | Wk].
__global__ void hist_build_kernel(const int* __restrict__ ei, int* __restrict__ hist_tot,
                                  int* __restrict__ hist_lo,
                                  const float* __restrict__ Wa, const float* __restrict__ Wk,
                                  float* __restrict__ Wh) {
    int e = blockIdx.x * blockDim.x + threadIdx.x;
    if (e < N_EDGES) {
        int s = ei[e];
        int d = ei[N_EDGES + e];
        atomicAdd(&hist_tot[d], 1);
        if (s < N_HALF) atomicAdd(&hist_lo[d], 1);
    }
    if (blockIdx.x == 0) {
        for (int idx = threadIdx.x; idx < H_DIM * 32; idx += 256) {
            int f = idx >> 5, c = idx & 31;
            Wh[idx] = (c < C_DIM) ? Wa[f * C_DIM + c] : Wk[f * C_DIM + (c - C_DIM)];
        }
    }
}

__global__ __launch_bounds__(1024) void scan_block_kernel(const int* __restrict__ hist,
                                                          int* __restrict__ excl,
                                                          int* __restrict__ partials) {
    __shared__ int buf[1024];
    int i = blockIdx.x * 1024 + threadIdx.x;
    int v = (i < N_NODES) ? hist[i] : 0;
    buf[threadIdx.x] = v;
    __syncthreads();
    for (int off = 1; off < 1024; off <<= 1) {
        int t = (threadIdx.x >= off) ? buf[threadIdx.x - off] : 0;
        __syncthreads();
        buf[threadIdx.x] += t;
        __syncthreads();
    }
    int incl = buf[threadIdx.x];
    if (i < N_NODES) excl[i] = incl - v;
    if (threadIdx.x == 1023) partials[blockIdx.x] = incl;
}

__global__ void scan_partials_kernel(int* __restrict__ partials) {
    int t = threadIdx.x;
    int orig = (t < 49) ? partials[t] : 0;
    int v = orig;
    for (int off = 1; off < 64; off <<= 1) {
        int u = __shfl_up(v, off, 64);
        if (t >= off) v += u;
    }
    if (t < 49) partials[t] = v - orig;
}

__global__ void scan_add_kernel(int* __restrict__ rowstart, const int* __restrict__ partials,
                                int* __restrict__ cursorA, int* __restrict__ split,
                                int* __restrict__ cursorB,
                                const int* __restrict__ hist_tot, const int* __restrict__ hist_lo,
                                float* __restrict__ dinv) {
    int i = blockIdx.x * blockDim.x + threadIdx.x;
    if (i < N_NODES) {
        int v = rowstart[i] + partials[i >> 10];
        rowstart[i] = v;
        cursorA[i]  = v;
        int sp = v + hist_lo[i];
        split[i]    = sp;
        cursorB[i]  = sp;
        dinv[i]     = rsqrtf((float)(hist_tot[i] + 1));
    } else if (i == N_NODES) {
        rowstart[i] = N_EDGES;
    }
}

// csr2[p] = (src, dinv[src]); lo-src edges pack to [rowstart, split), hi to [split, end).
__global__ void scatter_kernel(const int* __restrict__ ei, int* __restrict__ cursorA,
                               int* __restrict__ cursorB, const float* __restrict__ dinv,
                               int2* __restrict__ csr2) {
    int e = blockIdx.x * blockDim.x + threadIdx.x;
    if (e < N_EDGES) {
        int s = ei[e];
        int d = ei[N_EDGES + e];
        int p = (s < N_HALF) ? atomicAdd(&cursorA[d], 1) : atomicAdd(&cursorB[d], 1);
        csr2[p] = make_int2(s, __float_as_int(dinv[s]));
    }
}

// Edge-gather loop over csr2[J0,J1), x4 ILP, int4-paired csr2 loads. acc0 pre-declared.
#define AGG_LOOP(TBL, STRIDE, CIDX, J0, J1)                                              \
    float acc1 = 0.f, acc2 = 0.f, acc3 = 0.f;                                            \
    int j = (J0);                                                                        \
    if ((j & 1) && j < (J1)) {                                                           \
        int2 e = csr2[j];                                                                \
        acc1 += __int_as_float(e.y) * b2f(TBL[(size_t)e.x * STRIDE + CIDX]);             \
        j++;                                                                             \
    }                                                                                    \
    for (; j + 3 < (J1); j += 4) {                                                       \
        int4 p01 = *(const int4*)&csr2[j];                                               \
        int4 p23 = *(const int4*)&csr2[j + 2];                                           \
        acc0 += __int_as_float(p01.y) * b2f(TBL[(size_t)p01.x * STRIDE + CIDX]);         \
        acc1 += __int_as_float(p01.w) * b2f(TBL[(size_t)p01.z * STRIDE + CIDX]);         \
        acc2 += __int_as_float(p23.y) * b2f(TBL[(size_t)p23.x * STRIDE + CIDX]);         \
        acc3 += __int_as_float(p23.w) * b2f(TBL[(size_t)p23.z * STRIDE + CIDX]);         \
    }                                                                                    \
    for (; j < (J1); j++) {                                                              \
        int2 e = csr2[j];                                                                \
        acc0 += __int_as_float(e.y) * b2f(TBL[(size_t)e.x * STRIDE + CIDX]);             \
    }                                                                                    \
    float aggsum = (acc0 + acc1) + (acc2 + acc3);

// ---------------- layer-1 GEMM: x[50000,256] @ W1[256,64] -> h1 (bf16) ----------------
// LDS-tiled, 4 rows x 4 cols per thread: 8 ds_read_b128 per 64 FMA.
#define G_ROWS 64
#define G_KCH  64
#define XS_LD  68   // 64 + 4 pad; rows stay 16B-aligned

__global__ __launch_bounds__(256) void gemm_k256_kernel(const float* __restrict__ x,
                                                        const float* __restrict__ W,
                                                        bf16* __restrict__ h1) {
    __shared__ float xs[G_ROWS * XS_LD];   // 17408 B
    __shared__ float ws[G_KCH * H_DIM];    // 16384 B
    int t = threadIdx.x;
    int row0 = blockIdx.x * G_ROWS;
    int c4 = (t & 15) * 4;
    int r4 = (t >> 4) * 4;

    float acc[4][4];
#pragma unroll
    for (int i = 0; i < 4; i++)
#pragma unroll
        for (int q = 0; q < 4; q++) acc[i][q] = 0.f;

    for (int c = 0; c < F_IN / G_KCH; c++) {
        int k0 = c * G_KCH;
        {   // stage W chunk 64x64, coalesced float4
            const float4* Wg = (const float4*)(W + k0 * H_DIM);
            float4* wl = (float4*)ws;
#pragma unroll
            for (int i = 0; i < 4; i++) wl[t + 256 * i] = Wg[t + 256 * i];
        }
        {   // stage x chunk 64x64: 4 threads/row, 4 float4 each
            int r = t >> 2, jj = (t & 3) * 16;
            int row = row0 + r;
            float4 v0 = make_float4(0.f, 0.f, 0.f, 0.f), v1 = v0, v2 = v0, v3 = v0;
            if (row < N_NODES) {
                const float4* xg = (const float4*)(x + (size_t)row * F_IN + k0 + jj);
                v0 = xg[0]; v1 = xg[1]; v2 = xg[2]; v3 = xg[3];
            }
            float4* xl = (float4*)&xs[r * XS_LD + jj];
            xl[0] = v0; xl[1] = v1; xl[2] = v2; xl[3] = v3;
        }
        __syncthreads();
#pragma unroll 4
        for (int kk = 0; kk < G_KCH; kk += 4) {
            float4 xv[4], wv[4];
#pragma unroll
            for (int i = 0; i < 4; i++) xv[i] = *(const float4*)&xs[(r4 + i) * XS_LD + kk];
#pragma unroll
            for (int q = 0; q < 4; q++) wv[q] = *(const float4*)&ws[(kk + q) * H_DIM + c4];
#pragma unroll
            for (int i = 0; i < 4; i++) {
                acc[i][0] += xv[i].x * wv[0].x + xv[i].y * wv[1].x + xv[i].z * wv[2].x + xv[i].w * wv[3].x;
                acc[i][1] += xv[i].x * wv[0].y + xv[i].y * wv[1].y + xv[i].z * wv[2].y + xv[i].w * wv[3].y;
                acc[i][2] += xv[i].x * wv[0].z + xv[i].y * wv[1].z + xv[i].z * wv[2].z + xv[i].w * wv[3].z;
                acc[i][3] += xv[i].x * wv[0].w + xv[i].y * wv[1].w + xv[i].z * wv[2].w + xv[i].w * wv[3].w;
            }
        }
        __syncthreads();
    }
#pragma unroll
    for (int i = 0; i < 4; i++) {
        int row = row0 + r4 + i;
        if (row < N_NODES) {
            ushort4 p = make_ushort4(f2b_u(acc[i][0]), f2b_u(acc[i][1]),
                                     f2b_u(acc[i][2]), f2b_u(acc[i][3]));
            *(ushort4*)&h1[(size_t)row * H_DIM + c4] = p;
        }
    }
}

// ---------------- pass A: gather lo-src half (table rows < N_HALF, 3.2MB L2-resident) ---
__global__ __launch_bounds__(256) void aggA_kernel(const bf16* __restrict__ h,
                                                   const int* __restrict__ rowstart,
                                                   const int* __restrict__ split,
                                                   const int2* __restrict__ csr2,
                                                   const float* __restrict__ dinv,
                                                   float* __restrict__ accbuf) {
    int lane = threadIdx.x & 63;
    int node = blockIdx.x * 4 + __builtin_amdgcn_readfirstlane(threadIdx.x >> 6);
    float dn = dinv[node];
    int s0 = rowstart[node], s1 = split[node];
    float acc0 = (node < N_HALF) ? dn * b2f(h[(size_t)node * H_DIM + lane]) : 0.f;
    AGG_LOOP(h, H_DIM, lane, s0, s1)
    __builtin_nontemporal_store(aggsum, &accbuf[(size_t)node * H_DIM + lane]);
}

// ---------------- pass B: gather hi-src half + bias(+relu) + fused 64x64 GEMM ----------
template <int RELU>
__global__ __launch_bounds__(256) void aggB_gemm_kernel(const bf16* __restrict__ h,
                                                        const int* __restrict__ rowstart,
                                                        const int* __restrict__ split,
                                                        const int2* __restrict__ csr2,
                                                        const float* __restrict__ dinv,
                                                        const float* __restrict__ accbuf,
                                                        const float* __restrict__ bagg,
                                                        const float* __restrict__ W,
                                                        bf16* __restrict__ hnext) {
    __shared__ float Wl[H_DIM * H_DIM];   // 16 KB
    int t = threadIdx.x;
    {
        const float4* Wg = (const float4*)W;
        float4* wl = (float4*)Wl;
#pragma unroll
        for (int i = 0; i < 4; i++) wl[t + 256 * i] = Wg[t + 256 * i];
    }
    __syncthreads();
    int lane = t & 63;
    int node = blockIdx.x * 4 + __builtin_amdgcn_readfirstlane(t >> 6);
    float dn = dinv[node];
    int s0 = split[node], s1 = rowstart[node + 1];
    float acc0 = __builtin_nontemporal_load(&accbuf[(size_t)node * H_DIM + lane]);
    if (node >= N_HALF) acc0 += dn * b2f(h[(size_t)node * H_DIM + lane]);
    AGG_LOOP(h, H_DIM, lane, s0, s1)
    float v = dn * aggsum + bagg[lane];
    if (RELU) v = fmaxf(v, 0.f);
    float o = 0.f;
#pragma unroll
    for (int f = 0; f < H_DIM; f++)
        o += __shfl(v, f, 64) * Wl[f * H_DIM + lane];
    hnext[(size_t)node * H_DIM + lane] = f2b(o);
}

// ---------------- pass B (layer 3): -> feat f32, featL/featH (32-wide bf16), zb --------
__global__ __launch_bounds__(256) void aggB_out_kernel(const bf16* __restrict__ h,
                                                       const int* __restrict__ rowstart,
                                                       const int* __restrict__ split,
                                                       const int2* __restrict__ csr2,
                                                       const float* __restrict__ dinv,
                                                       const float* __restrict__ accbuf,
                                                       const float* __restrict__ b3,
                                                       const float* __restrict__ Wh,
                                                       float* __restrict__ feat,
                                                       bf16* __restrict__ featL,
                                                       bf16* __restrict__ featH,
                                                       bf16* __restrict__ zb) {
    __shared__ float Whs[H_DIM * 32];   // 8 KB
    int t = threadIdx.x;
    {
        const float4* Wg = (const float4*)Wh;
        float4* wl = (float4*)Whs;
#pragma unroll
        for (int i = 0; i < 2; i++) wl[t + 256 * i] = Wg[t + 256 * i];
    }
    __syncthreads();
    int lane = t & 63;
    int node = blockIdx.x * 4 + __builtin_amdgcn_readfirstlane(t >> 6);
    float dn = dinv[node];
    int s0 = split[node], s1 = rowstart[node + 1];
    float acc0 = __builtin_nontemporal_load(&accbuf[(size_t)node * H_DIM + lane]);
    if (node >= N_HALF) acc0 += dn * b2f(h[(size_t)node * H_DIM + lane]);
    AGG_LOOP(h, H_DIM, lane, s0, s1)
    float v = dn * aggsum + b3[lane];
    feat[(size_t)node * H_DIM + lane] = v;
    int c32 = lane & 31;
    bf16* half_tbl = (lane >= 32) ? featH : featL;
    half_tbl[(size_t)node * 32 + c32] = f2b(v);
    float zc = 0.f;
#pragma unroll
    for (int f = 0; f < H_DIM; f++)
        zc += __shfl(v, f, 64) * Whs[f * 32 + c32];
    if (lane < 32) zb[(size_t)node * 32 + lane] = f2b(zc);
}

// ---------------- head: aggregate zb (32-wide, 3.2MB L2-resident) ----------------------
__global__ __launch_bounds__(256) void head_kernel(const bf16* __restrict__ zb,
                                                   const int* __restrict__ rowstart,
                                                   const int2* __restrict__ csr2,
                                                   const float* __restrict__ dinv,
                                                   const float* __restrict__ ba,
                                                   const float* __restrict__ bk,
                                                   float* __restrict__ lsm,
                                                   float* __restrict__ att) {
    int t = threadIdx.x;
    int lane = t & 63;
    int half = lane >> 5;
    int c32 = lane & 31;
    int wid = __builtin_amdgcn_readfirstlane(t >> 6);
    int node = blockIdx.x * 8 + wid * 2 + half;
    float dn = dinv[node];
    int s0 = rowstart[node], s1 = rowstart[node + 1];
    float acc0 = dn * b2f(zb[(size_t)node * 32 + c32]);
    AGG_LOOP(zb, 32, c32, s0, s1)
    float y = dn * aggsum;
    int c = c32 & 15;
    float hv = y + ((c32 < 16) ? ba[c] : bk[c]);
    if (c32 < 16) {
        float m = hv;
#pragma unroll
        for (int off = 1; off < 16; off <<= 1) m = fmaxf(m, __shfl_xor(m, off, 64));
        float e = __expf(hv - m);
        float sum = e;
#pragma unroll
        for (int off = 1; off < 16; off <<= 1) sum += __shfl_xor(sum, off, 64);
        lsm[(size_t)node * C_DIM + c] = (hv - m) - __logf(sum);
    } else {
        att[(size_t)node * C_DIM + c] = hv;
    }
}

// ---------------- edge dot: 4 lanes/edge on a 32-wide half-table; 2 phases -------------
__global__ __launch_bounds__(256) void edge_dot_kernel(const int* __restrict__ pos,
                                                       const int* __restrict__ neg,
                                                       const bf16* __restrict__ tbl,
                                                       float* __restrict__ res,
                                                       int accumulate) {
    int e = blockIdx.x * 64 + (threadIdx.x >> 2);
    int lane4 = threadIdx.x & 3;
    int a, b;
    if (e < PE_CNT) {
        a = pos[e];
        b = pos[PE_CNT + e];
    } else {
        int e2 = e - PE_CNT;
        a = neg[e2];
        b = neg[PE_CNT + e2];
    }
    uint4 ua = ((const uint4*)(tbl + (size_t)a * 32))[lane4];
    uint4 ub = ((const uint4*)(tbl + (size_t)b * 32))[lane4];
    float s = 0.f;
    unsigned au, bu;
    au = ua.x; bu = ub.x;
    s += __uint_as_float(au << 16) * __uint_as_float(bu << 16);
    s += __uint_as_float(au & 0xffff0000u) * __uint_as_float(bu & 0xffff0000u);
    au = ua.y; bu = ub.y;
    s += __uint_as_float(au << 16) * __uint_as_float(bu << 16);
    s += __uint_as_float(au & 0xffff0000u) * __uint_as_float(bu & 0xffff0000u);
    au = ua.z; bu = ub.z;
    s += __uint_as_float(au << 16) * __uint_as_float(bu << 16);
    s += __uint_as_float(au & 0xffff0000u) * __uint_as_float(bu & 0xffff0000u);
    au = ua.w; bu = ub.w;
    s += __uint_as_float(au << 16) * __uint_as_float(bu << 16);
    s += __uint_as_float(au & 0xffff0000u) * __uint_as_float(bu & 0xffff0000u);
#pragma unroll
    for (int off = 1; off < 4; off <<= 1) s += __shfl_xor(s, off, 64);
    if (lane4 == 0) {
        if (accumulate) res[e] += s;
        else            res[e]  = s;
    }
}

// ---------------- launch ----------------

extern "C" void kernel_launch(void* const* d_in, const int* in_sizes, int n_in,
                              void* d_out, int out_size, void* d_ws, size_t ws_size,
                              hipStream_t stream) {
    const float* input = (const float*)d_in[0];
    // d_in[1] = glove = identity: x @ glove == x, skipped exactly.
    const float* W1 = (const float*)d_in[2];
    const float* b1 = (const float*)d_in[3];
    const float* W2 = (const float*)d_in[4];
    const float* b2 = (const float*)d_in[5];
    const float* W3 = (const float*)d_in[6];
    const float* b3 = (const float*)d_in[7];
    const float* Wa = (const float*)d_in[8];
    const float* ba = (const float*)d_in[9];
    const float* Wk = (const float*)d_in[10];
    const float* bk = (const float*)d_in[11];
    const int* ei  = (const int*)d_in[12];
    const int* pos = (const int*)d_in[13];
    const int* neg = (const int*)d_in[14];

    char* ws = (char*)d_ws;
    int*   hist_tot = (int*)(ws + 0);                 // 200000
    int*   hist_lo  = (int*)(ws + 200704);            // 200000
    int*   rowstart = (int*)(ws + 401408);            // 200004
    int*   cursorA  = (int*)(ws + 602112);            // 200000
    int*   split    = (int*)(ws + 802816);            // 200000
    int*   cursorB  = (int*)(ws + 1003520);           // 200000
    float* dinv     = (float*)(ws + 1204224);         // 200000
    int*   partials = (int*)(ws + 1404928);           // 256
    float* Wh       = (float*)(ws + 1405184);         // 8192
    int2*  csr2     = (int2*)(ws + 1413376);          // 6.4 MB
    bf16*  bufA     = (bf16*)(ws + 7813376ULL);       // 6.4 MB
    bf16*  bufB     = (bf16*)(ws + 14213376ULL);      // 6.4 MB
    bf16*  zb       = (bf16*)(ws + 20613376ULL);      // 3.2 MB
    bf16*  featL    = (bf16*)(ws + 23813376ULL);      // 3.2 MB
    bf16*  featH    = (bf16*)(ws + 27013376ULL);      // 3.2 MB
    float* accbuf   = (float*)(ws + 30213376ULL);     // 12.8 MB (end ~43 MB)

    float* out  = (float*)d_out;
    float* res  = out;                  // 400000
    float* lsm  = out + 400000;         // 800000
    float* att  = out + 1200000;        // 800000
    float* feat = out + 2000000;        // 3200000

    // CSR build (lo/hi partitioned rows)
    hipMemsetAsync(hist_tot, 0, 401408, stream);   // covers hist_tot + hist_lo
    hist_build_kernel<<<3125, 256, 0, stream>>>(ei, hist_tot, hist_lo, Wa, Wk, Wh);
    scan_block_kernel<<<49, 1024, 0, stream>>>(hist_tot, rowstart, partials);
    scan_partials_kernel<<<1, 64, 0, stream>>>(partials);
    scan_add_kernel<<<196, 256, 0, stream>>>(rowstart, partials, cursorA, split, cursorB,
                                             hist_tot, hist_lo, dinv);
    scatter_kernel<<<3125, 256, 0, stream>>>(ei, cursorA, cursorB, dinv, csr2);

    // layer 1 GEMM (f32 in, bf16 out)
    gemm_k256_kernel<<<(N_NODES + G_ROWS - 1) / G_ROWS, 256, 0, stream>>>(input, W1, bufA);

    // layer 1: aggA (lo half) -> accbuf ; aggB (hi half) + b1 + relu + @W2 -> bufB
    aggA_kernel<<<12500, 256, 0, stream>>>(bufA, rowstart, split, csr2, dinv, accbuf);
    aggB_gemm_kernel<1><<<12500, 256, 0, stream>>>(bufA, rowstart, split, csr2, dinv,
                                                   accbuf, b1, W2, bufB);
    // layer 2
    aggA_kernel<<<12500, 256, 0, stream>>>(bufB, rowstart, split, csr2, dinv, accbuf);
    aggB_gemm_kernel<0><<<12500, 256, 0, stream>>>(bufB, rowstart, split, csr2, dinv,
                                                   accbuf, b2, W3, bufA);
    // layer 3 -> feat, featL/featH, zb
    aggA_kernel<<<12500, 256, 0, stream>>>(bufA, rowstart, split, csr2, dinv, accbuf);
    aggB_out_kernel<<<12500, 256, 0, stream>>>(bufA, rowstart, split, csr2, dinv,
                                               accbuf, b3, Wh, feat, featL, featH, zb);
    // heads on zb (32-wide gather)
    head_kernel<<<6250, 256, 0, stream>>>(zb, rowstart, csr2, dinv, ba, bk, lsm, att);
    // edge dot: two 32-feature phases over L2-resident half-tables
    edge_dot_kernel<<<6250, 256, 0, stream>>>(pos, neg, featL, res, 0);
    edge_dot_kernel<<<6250, 256, 0, stream>>>(pos, neg, featH, res, 1);
}

// Round 8
// 457.878 us; speedup vs baseline: 1.1359x; 1.1359x over previous
//
#include <hip/hip_runtime.h>
#include <hip/hip_bf16.h>

#define N_NODES 50000
#define N_EDGES 800000
#define F_IN    256
#define H_DIM   64
#define C_DIM   16
#define PE_CNT  200000

typedef __hip_bfloat16 bf16;

__device__ __forceinline__ float b2f(bf16 v) { return __bfloat162float(v); }
__device__ __forceinline__ bf16  f2b(float v) { return __float2bfloat16(v); }
__device__ __forceinline__ unsigned short f2b_u(float v) {
    union { bf16 b; unsigned short u; } cv; cv.b = __float2bfloat16(v); return cv.u;
}

// ---------------- CSR build ----------------

// hist over dst; block 0 additionally packs Wh[64][32] = [Wa | Wk].
__global__ void hist_build_kernel(const int* __restrict__ dst, int* __restrict__ hist,
                                  const float* __restrict__ Wa, const float* __restrict__ Wk,
                                  float* __restrict__ Wh) {
    int e = blockIdx.x * blockDim.x + threadIdx.x;
    if (e < N_EDGES) atomicAdd(&hist[dst[e]], 1);
    if (blockIdx.x == 0) {
        for (int idx = threadIdx.x; idx < H_DIM * 32; idx += 256) {
            int f = idx >> 5, c = idx & 31;
            Wh[idx] = (c < C_DIM) ? Wa[f * C_DIM + c] : Wk[f * C_DIM + (c - C_DIM)];
        }
    }
}

__global__ __launch_bounds__(1024) void scan_block_kernel(const int* __restrict__ hist,
                                                          int* __restrict__ excl,
                                                          int* __restrict__ partials) {
    __shared__ int buf[1024];
    int i = blockIdx.x * 1024 + threadIdx.x;
    int v = (i < N_NODES) ? hist[i] : 0;
    buf[threadIdx.x] = v;
    __syncthreads();
    for (int off = 1; off < 1024; off <<= 1) {
        int t = (threadIdx.x >= off) ? buf[threadIdx.x - off] : 0;
        __syncthreads();
        buf[threadIdx.x] += t;
        __syncthreads();
    }
    int incl = buf[threadIdx.x];
    if (i < N_NODES) excl[i] = incl - v;
    if (threadIdx.x == 1023) partials[blockIdx.x] = incl;
}

__global__ void scan_partials_kernel(int* __restrict__ partials) {
    int t = threadIdx.x;
    int orig = (t < 49) ? partials[t] : 0;
    int v = orig;
    for (int off = 1; off < 64; off <<= 1) {
        int u = __shfl_up(v, off, 64);
        if (t >= off) v += u;
    }
    if (t < 49) partials[t] = v - orig;
}

__global__ void scan_add_kernel(int* __restrict__ rowstart, const int* __restrict__ partials,
                                int* __restrict__ cursor, const int* __restrict__ hist,
                                float* __restrict__ dinv) {
    int i = blockIdx.x * blockDim.x + threadIdx.x;
    if (i < N_NODES) {
        int v = rowstart[i] + partials[i >> 10];
        rowstart[i] = v;
        cursor[i]   = v;
        dinv[i]     = rsqrtf((float)(hist[i] + 1));
    } else if (i == N_NODES) {
        rowstart[i] = N_EDGES;
    }
}

// csr2[p] = (src, dinv[src]) — one 8B record per edge.
__global__ void scatter_kernel(const int* __restrict__ ei, int* __restrict__ cursor,
                               const float* __restrict__ dinv, int2* __restrict__ csr2) {
    int e = blockIdx.x * blockDim.x + threadIdx.x;
    if (e < N_EDGES) {
        int s = ei[e];
        int d = ei[N_EDGES + e];
        int p = atomicAdd(&cursor[d], 1);
        csr2[p] = make_int2(s, __float_as_int(dinv[s]));
    }
}

// Edge-gather loop over csr2[J0,J1), x4 ILP, int4-paired csr2 loads. acc0 pre-declared.
#define AGG_LOOP(TBL, STRIDE, CIDX, J0, J1)                                              \
    float acc1 = 0.f, acc2 = 0.f, acc3 = 0.f;                                            \
    int j = (J0);                                                                        \
    if ((j & 1) && j < (J1)) {                                                           \
        int2 e = csr2[j];                                                                \
        acc1 += __int_as_float(e.y) * b2f(TBL[(size_t)e.x * STRIDE + CIDX]);             \
        j++;                                                                             \
    }                                                                                    \
    for (; j + 3 < (J1); j += 4) {                                                       \
        int4 p01 = *(const int4*)&csr2[j];                                               \
        int4 p23 = *(const int4*)&csr2[j + 2];                                           \
        acc0 += __int_as_float(p01.y) * b2f(TBL[(size_t)p01.x * STRIDE + CIDX]);         \
        acc1 += __int_as_float(p01.w) * b2f(TBL[(size_t)p01.z * STRIDE + CIDX]);         \
        acc2 += __int_as_float(p23.y) * b2f(TBL[(size_t)p23.x * STRIDE + CIDX]);         \
        acc3 += __int_as_float(p23.w) * b2f(TBL[(size_t)p23.z * STRIDE + CIDX]);         \
    }                                                                                    \
    for (; j < (J1); j++) {                                                              \
        int2 e = csr2[j];                                                                \
        acc0 += __int_as_float(e.y) * b2f(TBL[(size_t)e.x * STRIDE + CIDX]);             \
    }                                                                                    \
    float aggsum = (acc0 + acc1) + (acc2 + acc3);

// ---------------- layer-1 GEMM: x[50000,256] @ W1[256,64] -> h1 (bf16) ----------------
// LDS-tiled, 4 rows x 4 cols per thread: 8 ds_read_b128 per 64 FMA.
#define G_ROWS 64
#define G_KCH  64
#define XS_LD  68   // 64 + 4 pad; rows stay 16B-aligned

__global__ __launch_bounds__(256) void gemm_k256_kernel(const float* __restrict__ x,
                                                        const float* __restrict__ W,
                                                        bf16* __restrict__ h1) {
    __shared__ float xs[G_ROWS * XS_LD];   // 17408 B
    __shared__ float ws[G_KCH * H_DIM];    // 16384 B
    int t = threadIdx.x;
    int row0 = blockIdx.x * G_ROWS;
    int c4 = (t & 15) * 4;
    int r4 = (t >> 4) * 4;

    float acc[4][4];
#pragma unroll
    for (int i = 0; i < 4; i++)
#pragma unroll
        for (int q = 0; q < 4; q++) acc[i][q] = 0.f;

    for (int c = 0; c < F_IN / G_KCH; c++) {
        int k0 = c * G_KCH;
        {   // stage W chunk 64x64, coalesced float4
            const float4* Wg = (const float4*)(W + k0 * H_DIM);
            float4* wl = (float4*)ws;
#pragma unroll
            for (int i = 0; i < 4; i++) wl[t + 256 * i] = Wg[t + 256 * i];
        }
        {   // stage x chunk 64x64: 4 threads/row, 4 float4 each
            int r = t >> 2, jj = (t & 3) * 16;
            int row = row0 + r;
            float4 v0 = make_float4(0.f, 0.f, 0.f, 0.f), v1 = v0, v2 = v0, v3 = v0;
            if (row < N_NODES) {
                const float4* xg = (const float4*)(x + (size_t)row * F_IN + k0 + jj);
                v0 = xg[0]; v1 = xg[1]; v2 = xg[2]; v3 = xg[3];
            }
            float4* xl = (float4*)&xs[r * XS_LD + jj];
            xl[0] = v0; xl[1] = v1; xl[2] = v2; xl[3] = v3;
        }
        __syncthreads();
#pragma unroll 4
        for (int kk = 0; kk < G_KCH; kk += 4) {
            float4 xv[4], wv[4];
#pragma unroll
            for (int i = 0; i < 4; i++) xv[i] = *(const float4*)&xs[(r4 + i) * XS_LD + kk];
#pragma unroll
            for (int q = 0; q < 4; q++) wv[q] = *(const float4*)&ws[(kk + q) * H_DIM + c4];
#pragma unroll
            for (int i = 0; i < 4; i++) {
                acc[i][0] += xv[i].x * wv[0].x + xv[i].y * wv[1].x + xv[i].z * wv[2].x + xv[i].w * wv[3].x;
                acc[i][1] += xv[i].x * wv[0].y + xv[i].y * wv[1].y + xv[i].z * wv[2].y + xv[i].w * wv[3].y;
                acc[i][2] += xv[i].x * wv[0].z + xv[i].y * wv[1].z + xv[i].z * wv[2].z + xv[i].w * wv[3].z;
                acc[i][3] += xv[i].x * wv[0].w + xv[i].y * wv[1].w + xv[i].z * wv[2].w + xv[i].w * wv[3].w;
            }
        }
        __syncthreads();
    }
#pragma unroll
    for (int i = 0; i < 4; i++) {
        int row = row0 + r4 + i;
        if (row < N_NODES) {
            ushort4 p = make_ushort4(f2b_u(acc[i][0]), f2b_u(acc[i][1]),
                                     f2b_u(acc[i][2]), f2b_u(acc[i][3]));
            *(ushort4*)&h1[(size_t)row * H_DIM + c4] = p;
        }
    }
}

// ---------------- fused agg + next-layer GEMM (W staged in LDS) ----------------
template <int RELU>
__global__ __launch_bounds__(256) void agg_gemm_kernel(const bf16* __restrict__ h,
                                                       const int* __restrict__ rowstart,
                                                       const int2* __restrict__ csr2,
                                                       const float* __restrict__ dinv,
                                                       const float* __restrict__ bagg,
                                                       const float* __restrict__ W,
                                                       bf16* __restrict__ hnext) {
    __shared__ float Wl[H_DIM * H_DIM];   // 16 KB
    int t = threadIdx.x;
    {
        const float4* Wg = (const float4*)W;
        float4* wl = (float4*)Wl;
#pragma unroll
        for (int i = 0; i < 4; i++) wl[t + 256 * i] = Wg[t + 256 * i];
    }
    __syncthreads();
    int lane = t & 63;
    int node = blockIdx.x * 4 + __builtin_amdgcn_readfirstlane(t >> 6);
    float dn = dinv[node];
    int s0 = rowstart[node], s1 = rowstart[node + 1];
    float acc0 = dn * b2f(h[(size_t)node * H_DIM + lane]);   // self loop
    AGG_LOOP(h, H_DIM, lane, s0, s1)
    float v = dn * aggsum + bagg[lane];
    if (RELU) v = fmaxf(v, 0.f);
    float o = 0.f;
#pragma unroll
    for (int f = 0; f < H_DIM; f++)
        o += __shfl(v, f, 64) * Wl[f * H_DIM + lane];
    hnext[(size_t)node * H_DIM + lane] = f2b(o);
}

// ---------------- layer-3 agg -> feat (f32) + featb (bf16) + zb = feat@Wh (bf16) -------
__global__ __launch_bounds__(256) void agg_out_kernel(const bf16* __restrict__ h,
                                                      const int* __restrict__ rowstart,
                                                      const int2* __restrict__ csr2,
                                                      const float* __restrict__ dinv,
                                                      const float* __restrict__ b3,
                                                      const float* __restrict__ Wh,
                                                      float* __restrict__ feat,
                                                      bf16* __restrict__ featb,
                                                      bf16* __restrict__ zb) {
    __shared__ float Whs[H_DIM * 32];   // 8 KB
    int t = threadIdx.x;
    {
        const float4* Wg = (const float4*)Wh;
        float4* wl = (float4*)Whs;
#pragma unroll
        for (int i = 0; i < 2; i++) wl[t + 256 * i] = Wg[t + 256 * i];
    }
    __syncthreads();
    int lane = t & 63;
    int node = blockIdx.x * 4 + __builtin_amdgcn_readfirstlane(t >> 6);
    float dn = dinv[node];
    int s0 = rowstart[node], s1 = rowstart[node + 1];
    float acc0 = dn * b2f(h[(size_t)node * H_DIM + lane]);
    AGG_LOOP(h, H_DIM, lane, s0, s1)
    float v = dn * aggsum + b3[lane];
    feat[(size_t)node * H_DIM + lane]  = v;
    featb[(size_t)node * H_DIM + lane] = f2b(v);
    int c32 = lane & 31;
    float zc = 0.f;
#pragma unroll
    for (int f = 0; f < H_DIM; f++)
        zc += __shfl(v, f, 64) * Whs[f * 32 + c32];
    if (lane < 32) zb[(size_t)node * 32 + lane] = f2b(zc);
}

// ---------------- head: aggregate zb (32-wide rows), biases + log-softmax --------------
// 32 lanes per node, 2 nodes per wave. cols 0-15 = attr (lsm), 16-31 = att.
__global__ __launch_bounds__(256) void head_kernel(const bf16* __restrict__ zb,
                                                   const int* __restrict__ rowstart,
                                                   const int2* __restrict__ csr2,
                                                   const float* __restrict__ dinv,
                                                   const float* __restrict__ ba,
                                                   const float* __restrict__ bk,
                                                   float* __restrict__ lsm,
                                                   float* __restrict__ att) {
    int t = threadIdx.x;
    int lane = t & 63;
    int half = lane >> 5;
    int c32 = lane & 31;
    int wid = __builtin_amdgcn_readfirstlane(t >> 6);
    int node = blockIdx.x * 8 + wid * 2 + half;
    float dn = dinv[node];
    int s0 = rowstart[node], s1 = rowstart[node + 1];
    float acc0 = dn * b2f(zb[(size_t)node * 32 + c32]);
    AGG_LOOP(zb, 32, c32, s0, s1)
    float y = dn * aggsum;
    int c = c32 & 15;
    float hv = y + ((c32 < 16) ? ba[c] : bk[c]);
    if (c32 < 16) {
        float m = hv;
#pragma unroll
        for (int off = 1; off < 16; off <<= 1) m = fmaxf(m, __shfl_xor(m, off, 64));
        float e = __expf(hv - m);
        float sum = e;
#pragma unroll
        for (int off = 1; off < 16; off <<= 1) sum += __shfl_xor(sum, off, 64);
        lsm[(size_t)node * C_DIM + c] = (hv - m) - __logf(sum);
    } else {
        att[(size_t)node * C_DIM + c] = hv;
    }
}

// ---------------- edge dot: 8 lanes/edge, uint4 (8 bf16) per lane ----------------
__global__ __launch_bounds__(256) void edge_dot_kernel(const int* __restrict__ pos,
                                                       const int* __restrict__ neg,
                                                       const bf16* __restrict__ xb,
                                                       float* __restrict__ res) {
    int e = blockIdx.x * 32 + (threadIdx.x >> 3);
    int lane8 = threadIdx.x & 7;
    int a, b;
    if (e < PE_CNT) {
        a = pos[e];
        b = pos[PE_CNT + e];
    } else {
        int e2 = e - PE_CNT;
        a = neg[e2];
        b = neg[PE_CNT + e2];
    }
    uint4 ua = ((const uint4*)(xb + (size_t)a * H_DIM))[lane8];
    uint4 ub = ((const uint4*)(xb + (size_t)b * H_DIM))[lane8];
    float s = 0.f;
    unsigned au, bu;
    au = ua.x; bu = ub.x;
    s += __uint_as_float(au << 16) * __uint_as_float(bu << 16);
    s += __uint_as_float(au & 0xffff0000u) * __uint_as_float(bu & 0xffff0000u);
    au = ua.y; bu = ub.y;
    s += __uint_as_float(au << 16) * __uint_as_float(bu << 16);
    s += __uint_as_float(au & 0xffff0000u) * __uint_as_float(bu & 0xffff0000u);
    au = ua.z; bu = ub.z;
    s += __uint_as_float(au << 16) * __uint_as_float(bu << 16);
    s += __uint_as_float(au & 0xffff0000u) * __uint_as_float(bu & 0xffff0000u);
    au = ua.w; bu = ub.w;
    s += __uint_as_float(au << 16) * __uint_as_float(bu << 16);
    s += __uint_as_float(au & 0xffff0000u) * __uint_as_float(bu & 0xffff0000u);
#pragma unroll
    for (int off = 1; off < 8; off <<= 1) s += __shfl_xor(s, off, 64);
    if (lane8 == 0) res[e] = s;
}

// ---------------- launch ----------------

extern "C" void kernel_launch(void* const* d_in, const int* in_sizes, int n_in,
                              void* d_out, int out_size, void* d_ws, size_t ws_size,
                              hipStream_t stream) {
    const float* input = (const float*)d_in[0];
    // d_in[1] = glove = identity: x @ glove == x, skipped exactly.
    const float* W1 = (const float*)d_in[2];
    const float* b1 = (const float*)d_in[3];
    const float* W2 = (const float*)d_in[4];
    const float* b2 = (const float*)d_in[5];
    const float* W3 = (const float*)d_in[6];
    const float* b3 = (const float*)d_in[7];
    const float* Wa = (const float*)d_in[8];
    const float* ba = (const float*)d_in[9];
    const float* Wk = (const float*)d_in[10];
    const float* bk = (const float*)d_in[11];
    const int* ei  = (const int*)d_in[12];
    const int* pos = (const int*)d_in[13];
    const int* neg = (const int*)d_in[14];

    char* ws = (char*)d_ws;
    int*   hist     = (int*)(ws + 0);                 // 200000
    int*   rowstart = (int*)(ws + 200704);            // 200004
    int*   cursor   = (int*)(ws + 401408);            // 200000
    float* dinv     = (float*)(ws + 602112);          // 200000
    int*   partials = (int*)(ws + 802816);            // 256
    float* Wh       = (float*)(ws + 803072);          // 8192
    int2*  csr2     = (int2*)(ws + 811264);           // 6.4 MB
    bf16*  bufA     = (bf16*)(ws + 7211264ULL);       // 6.4 MB
    bf16*  bufB     = (bf16*)(ws + 13611264ULL);      // 6.4 MB
    bf16*  zb       = (bf16*)(ws + 20013056ULL);      // 3.2 MB (end ~23.2 MB)

    float* out  = (float*)d_out;
    float* res  = out;                  // 400000
    float* lsm  = out + 400000;         // 800000
    float* att  = out + 1200000;        // 800000
    float* feat = out + 2000000;        // 3200000

    // CSR build (+ Wh pack piggybacked on block 0 of hist)
    hipMemsetAsync(hist, 0, N_NODES * sizeof(int), stream);
    hist_build_kernel<<<(N_EDGES + 255) / 256, 256, 0, stream>>>(ei + N_EDGES, hist, Wa, Wk, Wh);
    scan_block_kernel<<<49, 1024, 0, stream>>>(hist, rowstart, partials);
    scan_partials_kernel<<<1, 64, 0, stream>>>(partials);
    scan_add_kernel<<<196, 256, 0, stream>>>(rowstart, partials, cursor, hist, dinv);
    scatter_kernel<<<(N_EDGES + 255) / 256, 256, 0, stream>>>(ei, cursor, dinv, csr2);

    // layer 1 GEMM (f32 in, bf16 out)
    gemm_k256_kernel<<<(N_NODES + G_ROWS - 1) / G_ROWS, 256, 0, stream>>>(input, W1, bufA);
    // layer 1 agg (+b1, relu) fused with layer-2 GEMM
    agg_gemm_kernel<1><<<12500, 256, 0, stream>>>(bufA, rowstart, csr2, dinv, b1, W2, bufB);
    // layer 2 agg (+b2) fused with layer-3 GEMM
    agg_gemm_kernel<0><<<12500, 256, 0, stream>>>(bufB, rowstart, csr2, dinv, b2, W3, bufA);
    // layer 3 agg (+b3) -> feat, featb, zb = feat@[Wa|Wk]
    agg_out_kernel<<<12500, 256, 0, stream>>>(bufA, rowstart, csr2, dinv, b3, Wh, feat, bufB, zb);
    // heads on zb (32-wide gather)
    head_kernel<<<6250, 256, 0, stream>>>(zb, rowstart, csr2, dinv, ba, bk, lsm, att);
    // edge dot on bf16 feat
    edge_dot_kernel<<<12500, 256, 0, stream>>>(pos, neg, bufB, res);
}

// Round 9
// 442.573 us; speedup vs baseline: 1.1752x; 1.0346x over previous
//
#include <hip/hip_runtime.h>
#include <hip/hip_bf16.h>

#define N_NODES 50000
#define N_EDGES 800000
#define F_IN    256
#define H_DIM   64
#define C_DIM   16
#define PE_CNT  200000

typedef __hip_bfloat16 bf16;

__device__ __forceinline__ float b2f(bf16 v) { return __bfloat162float(v); }
__device__ __forceinline__ bf16  f2b(float v) { return __float2bfloat16(v); }
__device__ __forceinline__ unsigned short f2b_u(float v) {
    union { bf16 b; unsigned short u; } cv; cv.b = __float2bfloat16(v); return cv.u;
}

// ---------------- CSR build ----------------

// hist over dst; block 0 additionally packs Wh[64][32] = [Wa | Wk].
__global__ void hist_build_kernel(const int* __restrict__ dst, int* __restrict__ hist,
                                  const float* __restrict__ Wa, const float* __restrict__ Wk,
                                  float* __restrict__ Wh) {
    int e = blockIdx.x * blockDim.x + threadIdx.x;
    if (e < N_EDGES) atomicAdd(&hist[dst[e]], 1);
    if (blockIdx.x == 0) {
        for (int idx = threadIdx.x; idx < H_DIM * 32; idx += 256) {
            int f = idx >> 5, c = idx & 31;
            Wh[idx] = (c < C_DIM) ? Wa[f * C_DIM + c] : Wk[f * C_DIM + (c - C_DIM)];
        }
    }
}

__global__ __launch_bounds__(1024) void scan_block_kernel(const int* __restrict__ hist,
                                                          int* __restrict__ excl,
                                                          int* __restrict__ partials) {
    __shared__ int buf[1024];
    int i = blockIdx.x * 1024 + threadIdx.x;
    int v = (i < N_NODES) ? hist[i] : 0;
    buf[threadIdx.x] = v;
    __syncthreads();
    for (int off = 1; off < 1024; off <<= 1) {
        int t = (threadIdx.x >= off) ? buf[threadIdx.x - off] : 0;
        __syncthreads();
        buf[threadIdx.x] += t;
        __syncthreads();
    }
    int incl = buf[threadIdx.x];
    if (i < N_NODES) excl[i] = incl - v;
    if (threadIdx.x == 1023) partials[blockIdx.x] = incl;
}

__global__ void scan_partials_kernel(int* __restrict__ partials) {
    int t = threadIdx.x;
    int orig = (t < 49) ? partials[t] : 0;
    int v = orig;
    for (int off = 1; off < 64; off <<= 1) {
        int u = __shfl_up(v, off, 64);
        if (t >= off) v += u;
    }
    if (t < 49) partials[t] = v - orig;
}

__global__ void scan_add_kernel(int* __restrict__ rowstart, const int* __restrict__ partials,
                                int* __restrict__ cursor, const int* __restrict__ hist,
                                float* __restrict__ dinv) {
    int i = blockIdx.x * blockDim.x + threadIdx.x;
    if (i < N_NODES) {
        int v = rowstart[i] + partials[i >> 10];
        rowstart[i] = v;
        cursor[i]   = v;
        dinv[i]     = rsqrtf((float)(hist[i] + 1));
    } else if (i == N_NODES) {
        rowstart[i] = N_EDGES;
    }
}

// csr2[p] = (src, dinv[src]) — one 8B record per edge.
__global__ void scatter_kernel(const int* __restrict__ ei, int* __restrict__ cursor,
                               const float* __restrict__ dinv, int2* __restrict__ csr2) {
    int e = blockIdx.x * blockDim.x + threadIdx.x;
    if (e < N_EDGES) {
        int s = ei[e];
        int d = ei[N_EDGES + e];
        int p = atomicAdd(&cursor[d], 1);
        csr2[p] = make_int2(s, __float_as_int(dinv[s]));
    }
}

// Edge-gather loop over csr2[J0,J1), x4 ILP, int4-paired csr2 loads. acc0 pre-declared.
#define AGG_LOOP(TBL, STRIDE, CIDX, J0, J1)                                              \
    float acc1 = 0.f, acc2 = 0.f, acc3 = 0.f;                                            \
    int j = (J0);                                                                        \
    if ((j & 1) && j < (J1)) {                                                           \
        int2 e = csr2[j];                                                                \
        acc1 += __int_as_float(e.y) * b2f(TBL[(size_t)e.x * STRIDE + CIDX]);             \
        j++;                                                                             \
    }                                                                                    \
    for (; j + 3 < (J1); j += 4) {                                                       \
        int4 p01 = *(const int4*)&csr2[j];                                               \
        int4 p23 = *(const int4*)&csr2[j + 2];                                           \
        acc0 += __int_as_float(p01.y) * b2f(TBL[(size_t)p01.x * STRIDE + CIDX]);         \
        acc1 += __int_as_float(p01.w) * b2f(TBL[(size_t)p01.z * STRIDE + CIDX]);         \
        acc2 += __int_as_float(p23.y) * b2f(TBL[(size_t)p23.x * STRIDE + CIDX]);         \
        acc3 += __int_as_float(p23.w) * b2f(TBL[(size_t)p23.z * STRIDE + CIDX]);         \
    }                                                                                    \
    for (; j < (J1); j++) {                                                              \
        int2 e = csr2[j];                                                                \
        acc0 += __int_as_float(e.y) * b2f(TBL[(size_t)e.x * STRIDE + CIDX]);             \
    }                                                                                    \
    float aggsum = (acc0 + acc1) + (acc2 + acc3);

// ---------------- layer-1 GEMM: x[50000,256] @ W1[256,64] -> h1 (bf16) ----------------
// LDS-tiled, 4 rows x 4 cols per thread: 8 ds_read_b128 per 64 FMA.
#define G_ROWS 64
#define G_KCH  64
#define XS_LD  68   // 64 + 4 pad; rows stay 16B-aligned

__global__ __launch_bounds__(256) void gemm_k256_kernel(const float* __restrict__ x,
                                                        const float* __restrict__ W,
                                                        bf16* __restrict__ h1) {
    __shared__ float xs[G_ROWS * XS_LD];   // 17408 B
    __shared__ float ws[G_KCH * H_DIM];    // 16384 B
    int t = threadIdx.x;
    int row0 = blockIdx.x * G_ROWS;
    int c4 = (t & 15) * 4;
    int r4 = (t >> 4) * 4;

    float acc[4][4];
#pragma unroll
    for (int i = 0; i < 4; i++)
#pragma unroll
        for (int q = 0; q < 4; q++) acc[i][q] = 0.f;

    for (int c = 0; c < F_IN / G_KCH; c++) {
        int k0 = c * G_KCH;
        {   // stage W chunk 64x64, coalesced float4
            const float4* Wg = (const float4*)(W + k0 * H_DIM);
            float4* wl = (float4*)ws;
#pragma unroll
            for (int i = 0; i < 4; i++) wl[t + 256 * i] = Wg[t + 256 * i];
        }
        {   // stage x chunk 64x64: 4 threads/row, 4 float4 each
            int r = t >> 2, jj = (t & 3) * 16;
            int row = row0 + r;
            float4 v0 = make_float4(0.f, 0.f, 0.f, 0.f), v1 = v0, v2 = v0, v3 = v0;
            if (row < N_NODES) {
                const float4* xg = (const float4*)(x + (size_t)row * F_IN + k0 + jj);
                v0 = xg[0]; v1 = xg[1]; v2 = xg[2]; v3 = xg[3];
            }
            float4* xl = (float4*)&xs[r * XS_LD + jj];
            xl[0] = v0; xl[1] = v1; xl[2] = v2; xl[3] = v3;
        }
        __syncthreads();
#pragma unroll 4
        for (int kk = 0; kk < G_KCH; kk += 4) {
            float4 xv[4], wv[4];
#pragma unroll
            for (int i = 0; i < 4; i++) xv[i] = *(const float4*)&xs[(r4 + i) * XS_LD + kk];
#pragma unroll
            for (int q = 0; q < 4; q++) wv[q] = *(const float4*)&ws[(kk + q) * H_DIM + c4];
#pragma unroll
            for (int i = 0; i < 4; i++) {
                acc[i][0] += xv[i].x * wv[0].x + xv[i].y * wv[1].x + xv[i].z * wv[2].x + xv[i].w * wv[3].x;
                acc[i][1] += xv[i].x * wv[0].y + xv[i].y * wv[1].y + xv[i].z * wv[2].y + xv[i].w * wv[3].y;
                acc[i][2] += xv[i].x * wv[0].z + xv[i].y * wv[1].z + xv[i].z * wv[2].z + xv[i].w * wv[3].z;
                acc[i][3] += xv[i].x * wv[0].w + xv[i].y * wv[1].w + xv[i].z * wv[2].w + xv[i].w * wv[3].w;
            }
        }
        __syncthreads();
    }
#pragma unroll
    for (int i = 0; i < 4; i++) {
        int row = row0 + r4 + i;
        if (row < N_NODES) {
            ushort4 p = make_ushort4(f2b_u(acc[i][0]), f2b_u(acc[i][1]),
                                     f2b_u(acc[i][2]), f2b_u(acc[i][3]));
            *(ushort4*)&h1[(size_t)row * H_DIM + c4] = p;
        }
    }
}

// ---------------- fused agg + next-layer GEMM ----------------
// Epilogue restructured: W column in 64 VGPRs (constant-indexed, no LDS), v broadcast
// via wave-uniform ds_read_b128 (17 LDS ops/node vs 128 for shfl+ds_read version).
template <int RELU>
__global__ __launch_bounds__(256) void agg_gemm_kernel(const bf16* __restrict__ h,
                                                       const int* __restrict__ rowstart,
                                                       const int2* __restrict__ csr2,
                                                       const float* __restrict__ dinv,
                                                       const float* __restrict__ bagg,
                                                       const float* __restrict__ W,
                                                       bf16* __restrict__ hnext) {
    __shared__ float vbuf[4][H_DIM];   // 1 KB, one row per wave
    int t = threadIdx.x;
    int lane = t & 63;
    int wid  = __builtin_amdgcn_readfirstlane(t >> 6);
    // W column `lane` into registers (coalesced per f; W is 16KB, L2-hot)
    float wcol[H_DIM];
#pragma unroll
    for (int f = 0; f < H_DIM; f++) wcol[f] = W[f * H_DIM + lane];

    int node = blockIdx.x * 4 + wid;
    float dn = dinv[node];
    int s0 = rowstart[node], s1 = rowstart[node + 1];
    float acc0 = dn * b2f(h[(size_t)node * H_DIM + lane]);   // self loop
    AGG_LOOP(h, H_DIM, lane, s0, s1)
    float v = dn * aggsum + bagg[lane];
    if (RELU) v = fmaxf(v, 0.f);
    vbuf[wid][lane] = v;                       // 1 ds_write, same-wave consume
    float o = 0.f;
#pragma unroll
    for (int kk = 0; kk < H_DIM; kk += 4) {
        float4 vf = *(const float4*)&vbuf[wid][kk];   // wave-uniform -> broadcast
        o += vf.x * wcol[kk] + vf.y * wcol[kk + 1] + vf.z * wcol[kk + 2] + vf.w * wcol[kk + 3];
    }
    hnext[(size_t)node * H_DIM + lane] = f2b(o);
}

// ---------------- layer-3 agg -> feat (f32) + featb (bf16) + zb = feat@Wh (bf16) -------
__global__ __launch_bounds__(256) void agg_out_kernel(const bf16* __restrict__ h,
                                                      const int* __restrict__ rowstart,
                                                      const int2* __restrict__ csr2,
                                                      const float* __restrict__ dinv,
                                                      const float* __restrict__ b3,
                                                      const float* __restrict__ Wh,
                                                      float* __restrict__ feat,
                                                      bf16* __restrict__ featb,
                                                      bf16* __restrict__ zb) {
    __shared__ float vbuf[4][H_DIM];   // 1 KB
    int t = threadIdx.x;
    int lane = t & 63;
    int wid  = __builtin_amdgcn_readfirstlane(t >> 6);
    int c32  = lane & 31;
    // Wh column c32 into registers (lanes 32-63 mirror 0-31)
    float wcol[H_DIM];
#pragma unroll
    for (int f = 0; f < H_DIM; f++) wcol[f] = Wh[f * 32 + c32];

    int node = blockIdx.x * 4 + wid;
    float dn = dinv[node];
    int s0 = rowstart[node], s1 = rowstart[node + 1];
    float acc0 = dn * b2f(h[(size_t)node * H_DIM + lane]);
    AGG_LOOP(h, H_DIM, lane, s0, s1)
    float v = dn * aggsum + b3[lane];
    feat[(size_t)node * H_DIM + lane]  = v;
    featb[(size_t)node * H_DIM + lane] = f2b(v);
    vbuf[wid][lane] = v;
    float zc = 0.f;
#pragma unroll
    for (int kk = 0; kk < H_DIM; kk += 4) {
        float4 vf = *(const float4*)&vbuf[wid][kk];   // broadcast
        zc += vf.x * wcol[kk] + vf.y * wcol[kk + 1] + vf.z * wcol[kk + 2] + vf.w * wcol[kk + 3];
    }
    if (lane < 32) zb[(size_t)node * 32 + lane] = f2b(zc);
}

// ---------------- head: aggregate zb (32-wide rows), biases + log-softmax --------------
// 32 lanes per node, 2 nodes per wave. cols 0-15 = attr (lsm), 16-31 = att.
__global__ __launch_bounds__(256) void head_kernel(const bf16* __restrict__ zb,
                                                   const int* __restrict__ rowstart,
                                                   const int2* __restrict__ csr2,
                                                   const float* __restrict__ dinv,
                                                   const float* __restrict__ ba,
                                                   const float* __restrict__ bk,
                                                   float* __restrict__ lsm,
                                                   float* __restrict__ att) {
    int t = threadIdx.x;
    int lane = t & 63;
    int half = lane >> 5;
    int c32 = lane & 31;
    int wid = __builtin_amdgcn_readfirstlane(t >> 6);
    int node = blockIdx.x * 8 + wid * 2 + half;
    float dn = dinv[node];
    int s0 = rowstart[node], s1 = rowstart[node + 1];
    float acc0 = dn * b2f(zb[(size_t)node * 32 + c32]);
    AGG_LOOP(zb, 32, c32, s0, s1)
    float y = dn * aggsum;
    int c = c32 & 15;
    float hv = y + ((c32 < 16) ? ba[c] : bk[c]);
    if (c32 < 16) {
        float m = hv;
#pragma unroll
        for (int off = 1; off < 16; off <<= 1) m = fmaxf(m, __shfl_xor(m, off, 64));
        float e = __expf(hv - m);
        float sum = e;
#pragma unroll
        for (int off = 1; off < 16; off <<= 1) sum += __shfl_xor(sum, off, 64);
        lsm[(size_t)node * C_DIM + c] = (hv - m) - __logf(sum);
    } else {
        att[(size_t)node * C_DIM + c] = hv;
    }
}

// ---------------- edge dot: 8 lanes/edge, uint4 (8 bf16) per lane ----------------
__global__ __launch_bounds__(256) void edge_dot_kernel(const int* __restrict__ pos,
                                                       const int* __restrict__ neg,
                                                       const bf16* __restrict__ xb,
                                                       float* __restrict__ res) {
    int e = blockIdx.x * 32 + (threadIdx.x >> 3);
    int lane8 = threadIdx.x & 7;
    int a, b;
    if (e < PE_CNT) {
        a = pos[e];
        b = pos[PE_CNT + e];
    } else {
        int e2 = e - PE_CNT;
        a = neg[e2];
        b = neg[PE_CNT + e2];
    }
    uint4 ua = ((const uint4*)(xb + (size_t)a * H_DIM))[lane8];
    uint4 ub = ((const uint4*)(xb + (size_t)b * H_DIM))[lane8];
    float s = 0.f;
    unsigned au, bu;
    au = ua.x; bu = ub.x;
    s += __uint_as_float(au << 16) * __uint_as_float(bu << 16);
    s += __uint_as_float(au & 0xffff0000u) * __uint_as_float(bu & 0xffff0000u);
    au = ua.y; bu = ub.y;
    s += __uint_as_float(au << 16) * __uint_as_float(bu << 16);
    s += __uint_as_float(au & 0xffff0000u) * __uint_as_float(bu & 0xffff0000u);
    au = ua.z; bu = ub.z;
    s += __uint_as_float(au << 16) * __uint_as_float(bu << 16);
    s += __uint_as_float(au & 0xffff0000u) * __uint_as_float(bu & 0xffff0000u);
    au = ua.w; bu = ub.w;
    s += __uint_as_float(au << 16) * __uint_as_float(bu << 16);
    s += __uint_as_float(au & 0xffff0000u) * __uint_as_float(bu & 0xffff0000u);
#pragma unroll
    for (int off = 1; off < 8; off <<= 1) s += __shfl_xor(s, off, 64);
    if (lane8 == 0) res[e] = s;
}

// ---------------- launch ----------------

extern "C" void kernel_launch(void* const* d_in, const int* in_sizes, int n_in,
                              void* d_out, int out_size, void* d_ws, size_t ws_size,
                              hipStream_t stream) {
    const float* input = (const float*)d_in[0];
    // d_in[1] = glove = identity: x @ glove == x, skipped exactly.
    const float* W1 = (const float*)d_in[2];
    const float* b1 = (const float*)d_in[3];
    const float* W2 = (const float*)d_in[4];
    const float* b2 = (const float*)d_in[5];
    const float* W3 = (const float*)d_in[6];
    const float* b3 = (const float*)d_in[7];
    const float* Wa = (const float*)d_in[8];
    const float* ba = (const float*)d_in[9];
    const float* Wk = (const float*)d_in[10];
    const float* bk = (const float*)d_in[11];
    const int* ei  = (const int*)d_in[12];
    const int* pos = (const int*)d_in[13];
    const int* neg = (const int*)d_in[14];

    char* ws = (char*)d_ws;
    int*   hist     = (int*)(ws + 0);                 // 200000
    int*   rowstart = (int*)(ws + 200704);            // 200004
    int*   cursor   = (int*)(ws + 401408);            // 200000
    float* dinv     = (float*)(ws + 602112);          // 200000
    int*   partials = (int*)(ws + 802816);            // 256
    float* Wh       = (float*)(ws + 803072);          // 8192
    int2*  csr2     = (int2*)(ws + 811264);           // 6.4 MB
    bf16*  bufA     = (bf16*)(ws + 7211264ULL);       // 6.4 MB
    bf16*  bufB     = (bf16*)(ws + 13611264ULL);      // 6.4 MB
    bf16*  zb       = (bf16*)(ws + 20013056ULL);      // 3.2 MB (end ~23.2 MB)

    float* out  = (float*)d_out;
    float* res  = out;                  // 400000
    float* lsm  = out + 400000;         // 800000
    float* att  = out + 1200000;        // 800000
    float* feat = out + 2000000;        // 3200000

    // CSR build (+ Wh pack piggybacked on block 0 of hist)
    hipMemsetAsync(hist, 0, N_NODES * sizeof(int), stream);
    hist_build_kernel<<<(N_EDGES + 255) / 256, 256, 0, stream>>>(ei + N_EDGES, hist, Wa, Wk, Wh);
    scan_block_kernel<<<49, 1024, 0, stream>>>(hist, rowstart, partials);
    scan_partials_kernel<<<1, 64, 0, stream>>>(partials);
    scan_add_kernel<<<196, 256, 0, stream>>>(rowstart, partials, cursor, hist, dinv);
    scatter_kernel<<<(N_EDGES + 255) / 256, 256, 0, stream>>>(ei, cursor, dinv, csr2);

    // layer 1 GEMM (f32 in, bf16 out)
    gemm_k256_kernel<<<(N_NODES + G_ROWS - 1) / G_ROWS, 256, 0, stream>>>(input, W1, bufA);
    // layer 1 agg (+b1, relu) fused with layer-2 GEMM
    agg_gemm_kernel<1><<<12500, 256, 0, stream>>>(bufA, rowstart, csr2, dinv, b1, W2, bufB);
    // layer 2 agg (+b2) fused with layer-3 GEMM
    agg_gemm_kernel<0><<<12500, 256, 0, stream>>>(bufB, rowstart, csr2, dinv, b2, W3, bufA);
    // layer 3 agg (+b3) -> feat, featb, zb = feat@[Wa|Wk]
    agg_out_kernel<<<12500, 256, 0, stream>>>(bufA, rowstart, csr2, dinv, b3, Wh, feat, bufB, zb);
    // heads on zb (32-wide gather)
    head_kernel<<<6250, 256, 0, stream>>>(zb, rowstart, csr2, dinv, ba, bk, lsm, att);
    // edge dot on bf16 feat
    edge_dot_kernel<<<12500, 256, 0, stream>>>(pos, neg, bufB, res);
}